// Round 1
// baseline (519.757 us; speedup 1.0000x reference)
//
#include <hip/hip_runtime.h>
#include <hip/hip_bf16.h>
#include <math.h>

#define DD 128
#define DH 64
#define MAXN_F (1.0f - 4e-3f)

__device__ inline float wsum(float v) {
#pragma unroll
    for (int off = 32; off > 0; off >>= 1) v += __shfl_xor(v, off, 64);
    return v;
}

__device__ inline unsigned encf(float x) {
    unsigned b = __float_as_uint(x);
    return (b & 0x80000000u) ? ~b : (b | 0x80000000u);
}
__device__ inline float decf(unsigned u) {
    return (u & 0x80000000u) ? __uint_as_float(u & 0x7FFFFFFFu) : __uint_as_float(~u);
}
#define ENC_NEG_INF 0x007FFFFFu

// ---------------- hyp bias: proj(expmap0(bias)) ----------------
__global__ void bias_k(const float* __restrict__ bias, float* __restrict__ hb,
                       float* __restrict__ hb2) {
    __shared__ float red[2];
    int tid = threadIdx.x;  // 0..127
    float b = bias[tid];
    float s = wsum(b * b);
    if ((tid & 63) == 0) red[tid >> 6] = s;
    __syncthreads();
    float S = red[0] + red[1];
    __syncthreads();
    float n = fmaxf(sqrtf(S), 1e-15f);
    float e = tanhf(n) * b / n;
    float s2 = wsum(e * e);
    if ((tid & 63) == 0) red[tid >> 6] = s2;
    __syncthreads();
    float ne = fmaxf(sqrtf(red[0] + red[1]), 1e-15f);
    __syncthreads();
    if (ne > MAXN_F) e *= MAXN_F / ne;
    hb[tid] = e;
    float s3 = wsum(e * e);
    if ((tid & 63) == 0) red[tid >> 6] = s3;
    __syncthreads();
    if (tid == 0) hb2[0] = red[0] + red[1];
}

// ---------------- GEMM: mx = x @ W^T  (fp32) ----------------
// block: 256 threads, 64 rows; x tile in LDS; thread computes 8 rows x 4 cols
__global__ __launch_bounds__(256) void gemm_k(const float* __restrict__ x,
                                              const float* __restrict__ W,
                                              float* __restrict__ mx, int n) {
    __shared__ float xs[64 * DD];  // 32 KB
    const int row0 = blockIdx.x * 64;
    const int tid = threadIdx.x;
    const float4* x4 = reinterpret_cast<const float4*>(x);
    float4* xs4 = reinterpret_cast<float4*>(xs);
#pragma unroll
    for (int j = 0; j < 8; ++j) {
        int idx = tid + j * 256;  // [0,2048)
        int r = idx >> 5;
        float4 v = make_float4(0.f, 0.f, 0.f, 0.f);
        if (row0 + r < n) v = x4[(size_t)(row0 + r) * 32 + (idx & 31)];
        xs4[idx] = v;
    }
    __syncthreads();
    const int c4 = tid & 31;   // base col
    const int rg = tid >> 5;   // row group 0..7
    float acc[8][4];
#pragma unroll
    for (int rr = 0; rr < 8; ++rr)
#pragma unroll
        for (int cc = 0; cc < 4; ++cc) acc[rr][cc] = 0.f;
    const float4* W4 = reinterpret_cast<const float4*>(W);
    for (int k4 = 0; k4 < 32; ++k4) {
        float4 w0 = W4[(c4 + 0) * 32 + k4];
        float4 w1 = W4[(c4 + 32) * 32 + k4];
        float4 w2 = W4[(c4 + 64) * 32 + k4];
        float4 w3 = W4[(c4 + 96) * 32 + k4];
#pragma unroll
        for (int rr = 0; rr < 8; ++rr) {
            float4 xv = xs4[(rg * 8 + rr) * 32 + k4];
            acc[rr][0] += xv.x * w0.x + xv.y * w0.y + xv.z * w0.z + xv.w * w0.w;
            acc[rr][1] += xv.x * w1.x + xv.y * w1.y + xv.z * w1.z + xv.w * w1.w;
            acc[rr][2] += xv.x * w2.x + xv.y * w2.y + xv.z * w2.z + xv.w * w2.w;
            acc[rr][3] += xv.x * w3.x + xv.y * w3.y + xv.z * w3.z + xv.w * w3.w;
        }
    }
#pragma unroll
    for (int rr = 0; rr < 8; ++rr) {
        int r = row0 + rg * 8 + rr;
        if (r < n) {
#pragma unroll
            for (int cc = 0; cc < 4; ++cc)
                mx[(size_t)r * DD + cc * 32 + c4] = acc[rr][cc];
        }
    }
}

// ---------------- node pipeline: matvec tail + bias add + logmap0 + att dots --
__global__ __launch_bounds__(256) void node_k(
    const float* __restrict__ x, const float* __restrict__ mx,
    const float* __restrict__ hb, const float* __restrict__ hb2p,
    const float* __restrict__ atti, const float* __restrict__ attj,
    float* __restrict__ xt, float* __restrict__ ai, float* __restrict__ aj, int n) {
    int wid = (blockIdx.x * 256 + threadIdx.x) >> 6;
    int lane = threadIdx.x & 63;
    if (wid >= n) return;
    size_t base = (size_t)wid * DD;
    float x0 = x[base + lane], x1 = x[base + 64 + lane];
    float m0 = mx[base + lane], m1 = mx[base + 64 + lane];
    float Sx = wsum(x0 * x0 + x1 * x1);
    float Sm = wsum(m0 * m0 + m1 * m1);
    float xn = fmaxf(sqrtf(Sx), 1e-15f);
    float mxn = fmaxf(sqrtf(Sm), 1e-15f);
    // mobius_matvec (c=1)
    float art = atanhf(fminf(xn, 1.f - 1e-7f));
    float tn = tanhf(mxn / xn * art);
    float r = (Sm == 0.f) ? 0.f : tn / mxn;
    float p0 = r * m0, p1 = r * m1;
    // proj
    float Sp = wsum(p0 * p0 + p1 * p1);
    float np = fmaxf(sqrtf(Sp), 1e-15f);
    if (np > MAXN_F) { float sc = MAXN_F / np; p0 *= sc; p1 *= sc; }
    // mobius_add(p, hb)
    float y0 = hb[lane], y1 = hb[64 + lane];
    float y2 = hb2p[0];
    float X2 = wsum(p0 * p0 + p1 * p1);
    float XY = wsum(p0 * y0 + p1 * y1);
    float ca = 1.f + 2.f * XY + y2;
    float cb = 1.f - X2;
    float dn = fmaxf(1.f + 2.f * XY + X2 * y2, 1e-15f);
    float h0 = (ca * p0 + cb * y0) / dn;
    float h1 = (ca * p1 + cb * y1) / dn;
    // proj
    float Sh = wsum(h0 * h0 + h1 * h1);
    float nh = fmaxf(sqrtf(Sh), 1e-15f);
    if (nh > MAXN_F) { float sc = MAXN_F / nh; h0 *= sc; h1 *= sc; nh = MAXN_F; }
    // logmap0
    float g = atanhf(fminf(nh, 1.f - 1e-7f)) / nh;
    float t0 = g * h0, t1 = g * h1;
    xt[base + lane] = t0;
    xt[base + 64 + lane] = t1;
    // attention per-head dots (head0 = elems 0..63, head1 = 64..127)
    float A0 = wsum(t0 * atti[lane]);
    float A1 = wsum(t1 * atti[64 + lane]);
    float B0 = wsum(t0 * attj[lane]);
    float B1 = wsum(t1 * attj[64 + lane]);
    if (lane == 0) {
        ai[(size_t)wid * 2] = A0; ai[(size_t)wid * 2 + 1] = A1;
        aj[(size_t)wid * 2] = B0; aj[(size_t)wid * 2 + 1] = B1;
    }
}

// ---------------- init: supp=0, den=0, amax=enc(-inf) ----------------
__global__ void init_k(float* __restrict__ supp, float* __restrict__ den,
                       unsigned* __restrict__ amax, size_t nsupp, size_t nden) {
    size_t stride = (size_t)gridDim.x * blockDim.x;
    for (size_t i = blockIdx.x * (size_t)blockDim.x + threadIdx.x; i < nsupp; i += stride) {
        supp[i] = 0.f;
        if (i < nden) { den[i] = 0.f; amax[i] = ENC_NEG_INF; }
    }
}

// ---------------- edge pass 1: logits + segment max ----------------
__global__ __launch_bounds__(256) void att_max_k(
    const int* __restrict__ eidx, const float* __restrict__ ai,
    const float* __restrict__ aj, float* __restrict__ alphap,
    unsigned* __restrict__ amax, int E, int n) {
    int e = blockIdx.x * 256 + threadIdx.x;
    if (e >= E + n) return;
    int t, s;
    if (e < E) { t = eidx[e]; s = eidx[E + e]; } else { t = e - E; s = t; }
    float2 vi = reinterpret_cast<const float2*>(ai)[t];
    float2 vj = reinterpret_cast<const float2*>(aj)[s];
    float a0 = vi.x + vj.x; a0 = a0 < 0.f ? 0.2f * a0 : a0;
    float a1 = vi.y + vj.y; a1 = a1 < 0.f ? 0.2f * a1 : a1;
    reinterpret_cast<float2*>(alphap)[e] = make_float2(a0, a1);
    atomicMax(&amax[(size_t)t * 2 + 0], encf(a0));
    atomicMax(&amax[(size_t)t * 2 + 1], encf(a1));
}

// ---------------- edge pass 2: exp + segment sum ----------------
__global__ __launch_bounds__(256) void att_exp_k(
    const int* __restrict__ eidx, const float* __restrict__ alphap,
    const unsigned* __restrict__ amax, float* __restrict__ exs,
    float* __restrict__ den, int E, int n) {
    int e = blockIdx.x * 256 + threadIdx.x;
    if (e >= E + n) return;
    int t = (e < E) ? eidx[e] : (e - E);
    float2 al = reinterpret_cast<const float2*>(alphap)[e];
    float m0 = decf(amax[(size_t)t * 2 + 0]);
    float m1 = decf(amax[(size_t)t * 2 + 1]);
    float e0 = expf(al.x - m0), e1 = expf(al.y - m1);
    reinterpret_cast<float2*>(exs)[e] = make_float2(e0, e1);
    atomicAdd(&den[(size_t)t * 2 + 0], e0);
    atomicAdd(&den[(size_t)t * 2 + 1], e1);
}

// ---------------- edge pass 3: weighted message aggregation ----------------
__global__ __launch_bounds__(256) void agg_k(
    const int* __restrict__ eidx, const float* __restrict__ exs,
    const float* __restrict__ den, const float* __restrict__ xt,
    float* __restrict__ supp, int E, int n) {
    int w = (blockIdx.x * 256 + threadIdx.x) >> 6;
    int lane = threadIdx.x & 63;
    if (w >= E + n) return;
    int t, s;
    if (w < E) { t = eidx[w]; s = eidx[E + w]; } else { t = w - E; s = t; }
    float2 ex = reinterpret_cast<const float2*>(exs)[w];
    float2 dnv = reinterpret_cast<const float2*>(den)[t];
    float w0 = 0.5f * ex.x / (dnv.x + 1e-16f);
    float w1 = 0.5f * ex.y / (dnv.y + 1e-16f);
    float v = w0 * xt[(size_t)s * DD + lane] + w1 * xt[(size_t)s * DD + 64 + lane];
    atomicAdd(&supp[(size_t)t * DH + lane], v);
}

// ---------------- final: expmap0/proj/logmap0/leaky/expmap0/proj ----------------
__global__ __launch_bounds__(256) void final_k(const float* __restrict__ supp,
                                               float* __restrict__ out, int n) {
    int w = (blockIdx.x * 256 + threadIdx.x) >> 6;
    int lane = threadIdx.x & 63;
    if (w >= n) return;
    float u = supp[(size_t)w * DH + lane];
    float Su = wsum(u * u);
    float nu = fmaxf(sqrtf(Su), 1e-15f);
    float e = tanhf(nu) * u / nu;
    float Se = wsum(e * e);
    float ne = fmaxf(sqrtf(Se), 1e-15f);
    if (ne > MAXN_F) e *= MAXN_F / ne;
    // logmap0 (recompute norm of projected vector)
    float Sh = wsum(e * e);
    float nh = fmaxf(sqrtf(Sh), 1e-15f);
    float g = atanhf(fminf(nh, 1.f - 1e-7f)) / nh;
    float ht = g * e;
    ht = ht < 0.f ? 0.01f * ht : ht;
    // expmap0 + proj (c_out = 1)
    float St = wsum(ht * ht);
    float nt = fmaxf(sqrtf(St), 1e-15f);
    float o = tanhf(nt) * ht / nt;
    float So = wsum(o * o);
    float no = fmaxf(sqrtf(So), 1e-15f);
    if (no > MAXN_F) o *= MAXN_F / no;
    out[(size_t)w * DH + lane] = o;
}

extern "C" void kernel_launch(void* const* d_in, const int* in_sizes, int n_in,
                              void* d_out, int out_size, void* d_ws, size_t ws_size,
                              hipStream_t stream) {
    const float* x    = (const float*)d_in[0];
    const int*   eidx = (const int*)d_in[1];
    const float* W    = (const float*)d_in[2];
    const float* bias = (const float*)d_in[3];
    const float* atti = (const float*)d_in[4];
    const float* attj = (const float*)d_in[5];
    float* out = (float*)d_out;

    const int n = in_sizes[0] / DD;      // 100000
    const int E = in_sizes[1] / 2;       // 600000
    const int tot = E + n;
    const size_t nf = (size_t)n;

    float* ws = (float*)d_ws;
    float* xt     = ws;                          // n*128
    float* mx     = ws + nf * DD;                // n*128 (reused below after node_k)
    float* supp   = mx;                          // n*64
    float* exs    = mx + nf * DH;                // tot*2
    float* alphap = exs + (size_t)tot * 2;       // tot*2
    float* ai     = ws + nf * 2 * DD;            // 2n
    float* aj     = ai + 2 * nf;                 // 2n
    float* denb   = aj + 2 * nf;                 // 2n
    unsigned* amax = (unsigned*)(denb + 2 * nf); // 2n
    float* hb     = (float*)(amax + 2 * nf);     // 128
    float* hb2    = hb + DD;                     // 1

    bias_k<<<1, 128, 0, stream>>>(bias, hb, hb2);
    gemm_k<<<(n + 63) / 64, 256, 0, stream>>>(x, W, mx, n);
    node_k<<<(n + 3) / 4, 256, 0, stream>>>(x, mx, hb, hb2, atti, attj, xt, ai, aj, n);
    init_k<<<4096, 256, 0, stream>>>(supp, denb, amax, nf * DH, nf * 2);
    att_max_k<<<(tot + 255) / 256, 256, 0, stream>>>(eidx, ai, aj, alphap, amax, E, n);
    att_exp_k<<<(tot + 255) / 256, 256, 0, stream>>>(eidx, alphap, amax, exs, denb, E, n);
    agg_k<<<(tot + 3) / 4, 256, 0, stream>>>(eidx, exs, denb, xt, supp, E, n);
    final_k<<<(n + 3) / 4, 256, 0, stream>>>(supp, out, n);
}

// Round 4
// 404.786 us; speedup vs baseline: 1.2840x; 1.2840x over previous
//
#include <hip/hip_runtime.h>
#include <hip/hip_bf16.h>
#include <math.h>

#define DD 128
#define DH 64
#define MAXN_F (1.0f - 4e-3f)

__device__ inline float wsum(float v) {
#pragma unroll
    for (int off = 32; off > 0; off >>= 1) v += __shfl_xor(v, off, 64);
    return v;
}
__device__ inline float wmax(float v) {
#pragma unroll
    for (int off = 32; off > 0; off >>= 1) v = fmaxf(v, __shfl_xor(v, off, 64));
    return v;
}
__device__ inline int wsumi(int v) {
#pragma unroll
    for (int off = 32; off > 0; off >>= 1) v += __shfl_xor(v, off, 64);
    return v;
}

// ---------------- hyp bias: proj(expmap0(bias)) ----------------
__global__ void bias_k(const float* __restrict__ bias, float* __restrict__ hb,
                       float* __restrict__ hb2) {
    __shared__ float red[2];
    int tid = threadIdx.x;  // 0..127
    float b = bias[tid];
    float s = wsum(b * b);
    if ((tid & 63) == 0) red[tid >> 6] = s;
    __syncthreads();
    float S = red[0] + red[1];
    __syncthreads();
    float n = fmaxf(sqrtf(S), 1e-15f);
    float e = tanhf(n) * b / n;
    float s2 = wsum(e * e);
    if ((tid & 63) == 0) red[tid >> 6] = s2;
    __syncthreads();
    float ne = fmaxf(sqrtf(red[0] + red[1]), 1e-15f);
    __syncthreads();
    if (ne > MAXN_F) e *= MAXN_F / ne;
    hb[tid] = e;
    float s3 = wsum(e * e);
    if ((tid & 63) == 0) red[tid >> 6] = s3;
    __syncthreads();
    if (tid == 0) hb2[0] = red[0] + red[1];
}

// ---------------- fused GEMM (mx = x@W^T) + node pipeline ----------------
// block 256 = 4 waves, 64 rows. x tile in LDS; after gemm, save per-row |x|^2,
// overwrite tile with mx, then per-wave epilogue: mobius_matvec tail + proj +
// mobius_add(bias) + proj + logmap0 + attention dots.
__global__ __launch_bounds__(256) void gemm_node_k(
    const float* __restrict__ x, const float* __restrict__ W,
    const float* __restrict__ hb, const float* __restrict__ hb2p,
    const float* __restrict__ atti, const float* __restrict__ attj,
    float* __restrict__ xt, float* __restrict__ ai, float* __restrict__ aj, int n) {
    __shared__ float xs[64 * DD];  // 32 KB
    __shared__ float sxr[64];
    const int row0 = blockIdx.x * 64;
    const int tid = threadIdx.x;
    const float4* x4 = reinterpret_cast<const float4*>(x);
    float4* xs4 = reinterpret_cast<float4*>(xs);
#pragma unroll
    for (int j = 0; j < 8; ++j) {
        int idx = tid + j * 256;  // [0,2048)
        int r = idx >> 5;
        float4 v = make_float4(0.f, 0.f, 0.f, 0.f);
        if (row0 + r < n) v = x4[(size_t)(row0 + r) * 32 + (idx & 31)];
        xs4[idx] = v;
    }
    __syncthreads();
    const int c4 = tid & 31;   // base col
    const int rg = tid >> 5;   // row group 0..7
    float acc[8][4];
#pragma unroll
    for (int rr = 0; rr < 8; ++rr)
#pragma unroll
        for (int cc = 0; cc < 4; ++cc) acc[rr][cc] = 0.f;
    const float4* W4 = reinterpret_cast<const float4*>(W);
    for (int k4 = 0; k4 < 32; ++k4) {
        float4 w0 = W4[(c4 + 0) * 32 + k4];
        float4 w1 = W4[(c4 + 32) * 32 + k4];
        float4 w2 = W4[(c4 + 64) * 32 + k4];
        float4 w3 = W4[(c4 + 96) * 32 + k4];
#pragma unroll
        for (int rr = 0; rr < 8; ++rr) {
            float4 xv = xs4[(rg * 8 + rr) * 32 + k4];
            acc[rr][0] += xv.x * w0.x + xv.y * w0.y + xv.z * w0.z + xv.w * w0.w;
            acc[rr][1] += xv.x * w1.x + xv.y * w1.y + xv.z * w1.z + xv.w * w1.w;
            acc[rr][2] += xv.x * w2.x + xv.y * w2.y + xv.z * w2.z + xv.w * w2.w;
            acc[rr][3] += xv.x * w3.x + xv.y * w3.y + xv.z * w3.z + xv.w * w3.w;
        }
    }
    // save per-row |x|^2 before overwriting the tile
    const int wv = tid >> 6;
    const int lane = tid & 63;
#pragma unroll
    for (int i = 0; i < 16; ++i) {
        int row = wv * 16 + i;
        float x0 = xs[row * DD + lane], x1 = xs[row * DD + 64 + lane];
        float S = wsum(x0 * x0 + x1 * x1);
        if (lane == 0) sxr[row] = S;
    }
    __syncthreads();
    // overwrite tile with mx
#pragma unroll
    for (int rr = 0; rr < 8; ++rr)
#pragma unroll
        for (int cc = 0; cc < 4; ++cc)
            xs[(rg * 8 + rr) * DD + cc * 32 + c4] = acc[rr][cc];
    __syncthreads();
    // epilogue: wave wv handles rows wv*16 .. wv*16+15
    float y0 = hb[lane], y1 = hb[64 + lane];
    float y2 = hb2p[0];
    float Ai0 = atti[lane], Ai1 = atti[64 + lane];
    float Aj0 = attj[lane], Aj1 = attj[64 + lane];
#pragma unroll 1
    for (int i = 0; i < 16; ++i) {
        int row = wv * 16 + i;
        int grow = row0 + row;
        if (grow >= n) continue;  // uniform per wave
        float m0 = xs[row * DD + lane], m1 = xs[row * DD + 64 + lane];
        float Sx = sxr[row];
        float Sm = wsum(m0 * m0 + m1 * m1);
        float xn = fmaxf(sqrtf(Sx), 1e-15f);
        float mxn = fmaxf(sqrtf(Sm), 1e-15f);
        float art = atanhf(fminf(xn, 1.f - 1e-7f));
        float tn = tanhf(mxn / xn * art);
        float r = (Sm == 0.f) ? 0.f : tn / mxn;
        float p0 = r * m0, p1 = r * m1;
        float Sp = wsum(p0 * p0 + p1 * p1);
        float np = fmaxf(sqrtf(Sp), 1e-15f);
        if (np > MAXN_F) { float sc = MAXN_F / np; p0 *= sc; p1 *= sc; }
        float X2 = wsum(p0 * p0 + p1 * p1);
        float XY = wsum(p0 * y0 + p1 * y1);
        float ca = 1.f + 2.f * XY + y2;
        float cb = 1.f - X2;
        float dn = fmaxf(1.f + 2.f * XY + X2 * y2, 1e-15f);
        float h0 = (ca * p0 + cb * y0) / dn;
        float h1 = (ca * p1 + cb * y1) / dn;
        float Sh = wsum(h0 * h0 + h1 * h1);
        float nh = fmaxf(sqrtf(Sh), 1e-15f);
        if (nh > MAXN_F) { float sc = MAXN_F / nh; h0 *= sc; h1 *= sc; nh = MAXN_F; }
        float g = atanhf(fminf(nh, 1.f - 1e-7f)) / nh;
        float t0 = g * h0, t1 = g * h1;
        size_t base = (size_t)grow * DD;
        xt[base + lane] = t0;
        xt[base + 64 + lane] = t1;
        float A0 = wsum(t0 * Ai0);
        float A1 = wsum(t1 * Ai1);
        float B0 = wsum(t0 * Aj0);
        float B1 = wsum(t1 * Aj1);
        if (lane == 0) {
            reinterpret_cast<float2*>(ai)[grow] = make_float2(A0, A1);
            reinterpret_cast<float2*>(aj)[grow] = make_float2(B0, B1);
        }
    }
}

// ---------------- CSR build: histogram ----------------
__global__ __launch_bounds__(256) void count_k(const int* __restrict__ eidx,
                                               int* __restrict__ deg, int E) {
    int e = blockIdx.x * 256 + threadIdx.x;
    if (e >= E) return;
    atomicAdd(&deg[eidx[e]], 1);
}

// ---------------- scan: 3-level exclusive prefix sum ----------------
__global__ __launch_bounds__(256) void scan1_k(const int* __restrict__ deg,
                                               int* __restrict__ bsum, int n) {
    int b = blockIdx.x, tid = threadIdx.x;
    int i0 = b * 1024 + tid * 4;
    int s = 0;
#pragma unroll
    for (int k = 0; k < 4; ++k)
        if (i0 + k < n) s += deg[i0 + k];
    s = wsumi(s);
    __shared__ int sm[4];
    if ((tid & 63) == 0) sm[tid >> 6] = s;
    __syncthreads();
    if (tid == 0) bsum[b] = sm[0] + sm[1] + sm[2] + sm[3];
}

__global__ __launch_bounds__(256) void scan2_k(const int* __restrict__ bsum,
                                               int* __restrict__ bsoff, int nb) {
    int tid = threadIdx.x;
    __shared__ int sm[256];
    int v = (tid < nb) ? bsum[tid] : 0;
    sm[tid] = v;
    __syncthreads();
    for (int off = 1; off < 256; off <<= 1) {
        int u = (tid >= off) ? sm[tid - off] : 0;
        __syncthreads();
        sm[tid] += u;
        __syncthreads();
    }
    if (tid < nb) bsoff[tid] = sm[tid] - v;
}

__global__ __launch_bounds__(256) void scan3_k(const int* __restrict__ deg,
                                               const int* __restrict__ bsoff,
                                               int* __restrict__ rowptr,
                                               int* __restrict__ cursor, int n, int E) {
    int b = blockIdx.x, tid = threadIdx.x;
    int i0 = b * 1024 + tid * 4;
    int d[4];
#pragma unroll
    for (int k = 0; k < 4; ++k) d[k] = (i0 + k < n) ? deg[i0 + k] : 0;
    int ts = d[0] + d[1] + d[2] + d[3];
    __shared__ int sm[256];
    sm[tid] = ts;
    __syncthreads();
    for (int off = 1; off < 256; off <<= 1) {
        int u = (tid >= off) ? sm[tid - off] : 0;
        __syncthreads();
        sm[tid] += u;
        __syncthreads();
    }
    int base = bsoff[b] + sm[tid] - ts;
    int pre = 0;
#pragma unroll
    for (int k = 0; k < 4; ++k) {
        if (i0 + k < n) {
            rowptr[i0 + k] = base + pre;
            cursor[i0 + k] = base + pre;
        }
        pre += d[k];
    }
    if (b == 0 && tid == 0) rowptr[n] = E;
}

// ---------------- CSR build: scatter ----------------
__global__ __launch_bounds__(256) void scatter_k(const int* __restrict__ eidx,
                                                 int* __restrict__ cursor,
                                                 int* __restrict__ csrc, int E) {
    int e = blockIdx.x * 256 + threadIdx.x;
    if (e >= E) return;
    int t = eidx[e], s = eidx[E + e];
    int pos = atomicAdd(&cursor[t], 1);
    csrc[pos] = s;
}

// ---------------- fused softmax + aggregation + HypAct ----------------
// one wave per target node; CSR gather, no atomics.
__global__ __launch_bounds__(256) void agg_fused_k(
    const int* __restrict__ rowptr, const int* __restrict__ csrc,
    const float* __restrict__ ai, const float* __restrict__ aj,
    const float* __restrict__ xt, float* __restrict__ out, int n) {
    int t = (blockIdx.x * 256 + threadIdx.x) >> 6;
    int lane = threadIdx.x & 63;
    if (t >= n) return;
    const int beg = rowptr[t];
    const int deg = rowptr[t + 1] - beg;
    const int cnt = deg + 1;  // + self loop
    float2 ait = reinterpret_cast<const float2*>(ai)[t];
    const float2* aj2 = reinterpret_cast<const float2*>(aj);
    // pass 1: segment max
    float mx0 = -1e30f, mx1 = -1e30f;
    for (int bs = 0; bs < cnt; bs += 64) {
        int idx = bs + lane;
        float a0 = -1e30f, a1 = -1e30f;
        if (idx < cnt) {
            int s = (idx < deg) ? csrc[beg + idx] : t;
            float2 av = aj2[s];
            a0 = ait.x + av.x; a0 = a0 < 0.f ? 0.2f * a0 : a0;
            a1 = ait.y + av.y; a1 = a1 < 0.f ? 0.2f * a1 : a1;
        }
        mx0 = fmaxf(mx0, a0);
        mx1 = fmaxf(mx1, a1);
    }
    mx0 = wmax(mx0);
    mx1 = wmax(mx1);
    // pass 2: exp weights + denominator + weighted gather
    float acc0 = 0.f, acc1 = 0.f, den0 = 0.f, den1 = 0.f;
    for (int bs = 0; bs < cnt; bs += 64) {
        int idx = bs + lane;
        int s = t;
        float e0 = 0.f, e1 = 0.f;
        if (idx < cnt) {
            s = (idx < deg) ? csrc[beg + idx] : t;
            float2 av = aj2[s];
            float a0 = ait.x + av.x; a0 = a0 < 0.f ? 0.2f * a0 : a0;
            float a1 = ait.y + av.y; a1 = a1 < 0.f ? 0.2f * a1 : a1;
            e0 = expf(a0 - mx0);
            e1 = expf(a1 - mx1);
        }
        den0 += e0;
        den1 += e1;
        int m = min(64, cnt - bs);
        for (int j = 0; j < m; ++j) {
            int sj = __shfl(s, j, 64);
            float w0 = __shfl(e0, j, 64);
            float w1 = __shfl(e1, j, 64);
            size_t sb = (size_t)sj * DD;
            acc0 += w0 * xt[sb + lane];
            acc1 += w1 * xt[sb + 64 + lane];
        }
    }
    den0 = wsum(den0);
    den1 = wsum(den1);
    float u = 0.5f * (acc0 / (den0 + 1e-16f) + acc1 / (den1 + 1e-16f));
    // ---- HypAct: expmap0 -> proj -> logmap0 -> leaky -> expmap0 -> proj ----
    float Su = wsum(u * u);
    float nu = fmaxf(sqrtf(Su), 1e-15f);
    float e = tanhf(nu) * u / nu;
    float Se = wsum(e * e);
    float ne = fmaxf(sqrtf(Se), 1e-15f);
    if (ne > MAXN_F) e *= MAXN_F / ne;
    float Sh = wsum(e * e);
    float nh = fmaxf(sqrtf(Sh), 1e-15f);
    float g = atanhf(fminf(nh, 1.f - 1e-7f)) / nh;
    float ht = g * e;
    ht = ht < 0.f ? 0.01f * ht : ht;
    float St = wsum(ht * ht);
    float nt = fmaxf(sqrtf(St), 1e-15f);
    float o = tanhf(nt) * ht / nt;
    float So = wsum(o * o);
    float no = fmaxf(sqrtf(So), 1e-15f);
    if (no > MAXN_F) o *= MAXN_F / no;
    out[(size_t)t * DH + lane] = o;
}

extern "C" void kernel_launch(void* const* d_in, const int* in_sizes, int n_in,
                              void* d_out, int out_size, void* d_ws, size_t ws_size,
                              hipStream_t stream) {
    const float* x    = (const float*)d_in[0];
    const int*   eidx = (const int*)d_in[1];
    const float* W    = (const float*)d_in[2];
    const float* bias = (const float*)d_in[3];
    const float* atti = (const float*)d_in[4];
    const float* attj = (const float*)d_in[5];
    float* out = (float*)d_out;

    const int n = in_sizes[0] / DD;  // 100000
    const int E = in_sizes[1] / 2;   // 600000
    const size_t nf = (size_t)n;

    float* ws = (float*)d_ws;
    float* xt  = ws;                   // n*128
    float* ai  = xt + nf * DD;         // 2n
    float* aj  = ai + 2 * nf;          // 2n
    float* hb  = aj + 2 * nf;          // 128
    float* hb2 = hb + DD;              // 1 (+15 pad)
    int* deg    = (int*)(hb2 + 15);    // n   (16B aligned: offset 132n+144 floats)
    int* rowptr = deg + nf;            // n+1
    int* cursor = rowptr + nf + 1;     // n
    int* bsum   = cursor + nf;         // 256
    int* bsoff  = bsum + 256;          // 256
    int* csrc   = bsoff + 256;         // E

    const int nb = (n + 1023) / 1024;  // scan blocks (<=256)

    hipMemsetAsync(deg, 0, nf * sizeof(int), stream);
    bias_k<<<1, 128, 0, stream>>>(bias, hb, hb2);
    gemm_node_k<<<(n + 63) / 64, 256, 0, stream>>>(x, W, hb, hb2, atti, attj,
                                                   xt, ai, aj, n);
    count_k<<<(E + 255) / 256, 256, 0, stream>>>(eidx, deg, E);
    scan1_k<<<nb, 256, 0, stream>>>(deg, bsum, n);
    scan2_k<<<1, 256, 0, stream>>>(bsum, bsoff, nb);
    scan3_k<<<nb, 256, 0, stream>>>(deg, bsoff, rowptr, cursor, n, E);
    scatter_k<<<(E + 255) / 256, 256, 0, stream>>>(eidx, cursor, csrc, E);
    agg_fused_k<<<(n + 3) / 4, 256, 0, stream>>>(rowptr, csrc, ai, aj, xt, out, n);
}

// Round 8
// 338.090 us; speedup vs baseline: 1.5373x; 1.1973x over previous
//
#include <hip/hip_runtime.h>
#include <hip/hip_bf16.h>
#include <math.h>

#define DD 128
#define DH 64
#define MAXN_F (1.0f - 4e-3f)

__device__ inline float wsum(float v) {
#pragma unroll
    for (int off = 32; off > 0; off >>= 1) v += __shfl_xor(v, off, 64);
    return v;
}
__device__ inline float wmax(float v) {
#pragma unroll
    for (int off = 32; off > 0; off >>= 1) v = fmaxf(v, __shfl_xor(v, off, 64));
    return v;
}
__device__ inline int wsumi(int v) {
#pragma unroll
    for (int off = 32; off > 0; off >>= 1) v += __shfl_xor(v, off, 64);
    return v;
}

// ---------------- hyp bias: proj(expmap0(bias)) + constants ----------------
// cst = { y2=|hb|^2, Yi0, Yi1, Yj0, Yj1 }  (per-head dots of hb with att vecs)
__global__ void bias_k(const float* __restrict__ bias,
                       const float* __restrict__ atti, const float* __restrict__ attj,
                       float* __restrict__ hb, float* __restrict__ cst) {
    __shared__ float red[2];
    int tid = threadIdx.x;  // 0..127
    float b = bias[tid];
    float s = wsum(b * b);
    if ((tid & 63) == 0) red[tid >> 6] = s;
    __syncthreads();
    float S = red[0] + red[1];
    __syncthreads();
    float n = fmaxf(sqrtf(S), 1e-15f);
    float e = tanhf(n) * b / n;
    float s2 = wsum(e * e);
    if ((tid & 63) == 0) red[tid >> 6] = s2;
    __syncthreads();
    float ne = fmaxf(sqrtf(red[0] + red[1]), 1e-15f);
    __syncthreads();
    if (ne > MAXN_F) e *= MAXN_F / ne;
    hb[tid] = e;
    float s3 = wsum(e * e);
    if ((tid & 63) == 0) red[tid >> 6] = s3;
    __syncthreads();
    if (tid == 0) cst[0] = red[0] + red[1];
    // per-head dots: wave 0 = head 0 (dims 0..63), wave 1 = head 1
    float di = wsum(e * atti[tid]);
    float dj = wsum(e * attj[tid]);
    if ((tid & 63) == 0) {
        int h = tid >> 6;
        cst[1 + h] = di;  // Yi0 / Yi1
        cst[3 + h] = dj;  // Yj0 / Yj1
    }
}

// ---------------- fused GEMM (mx = x@W^T) + analytic node epilogue ----------
// block 256 = 4 waves, 64 rows. After GEMM, per-row quantities are computed as
// BATCHED quarter-row serial sums (no cross-lane shuffle chains); all hyperbolic
// maps collapse to scalars: xt_row = alpha*mx_row + beta*hb.
__global__ __launch_bounds__(256) void gemm_node_k(
    const float* __restrict__ x, const float* __restrict__ W,
    const float* __restrict__ hb, const float* __restrict__ cst,
    const float* __restrict__ atti, const float* __restrict__ attj,
    float* __restrict__ xt, float* __restrict__ ai, float* __restrict__ aj, int n) {
    __shared__ float xs[64 * DD];        // 32 KB tile (x, then mx)
    __shared__ float sred[64 * 4 * 4];   // (r*4+q)*4 + {Sm,My,Di,Dj}
    __shared__ float sxq[64 * 4];        // |x|^2 quarter partials
    __shared__ float sab[64 * 2];        // alpha,beta per row
    const int row0 = blockIdx.x * 64;
    const int tid = threadIdx.x;
    const float4* x4 = reinterpret_cast<const float4*>(x);
    float4* xs4 = reinterpret_cast<float4*>(xs);
#pragma unroll
    for (int j = 0; j < 8; ++j) {
        int idx = tid + j * 256;  // [0,2048)
        int r = idx >> 5;
        float4 v = make_float4(0.f, 0.f, 0.f, 0.f);
        if (row0 + r < n) v = x4[(size_t)(row0 + r) * 32 + (idx & 31)];
        xs4[idx] = v;
    }
    __syncthreads();
    const int c4 = tid & 31;   // base col
    const int rg = tid >> 5;   // row group 0..7
    float acc[8][4];
#pragma unroll
    for (int rr = 0; rr < 8; ++rr)
#pragma unroll
        for (int cc = 0; cc < 4; ++cc) acc[rr][cc] = 0.f;
    const float4* W4 = reinterpret_cast<const float4*>(W);
    for (int k4 = 0; k4 < 32; ++k4) {
        float4 w0 = W4[(c4 + 0) * 32 + k4];
        float4 w1 = W4[(c4 + 32) * 32 + k4];
        float4 w2 = W4[(c4 + 64) * 32 + k4];
        float4 w3 = W4[(c4 + 96) * 32 + k4];
#pragma unroll
        for (int rr = 0; rr < 8; ++rr) {
            float4 xv = xs4[(rg * 8 + rr) * 32 + k4];
            acc[rr][0] += xv.x * w0.x + xv.y * w0.y + xv.z * w0.z + xv.w * w0.w;
            acc[rr][1] += xv.x * w1.x + xv.y * w1.y + xv.z * w1.z + xv.w * w1.w;
            acc[rr][2] += xv.x * w2.x + xv.y * w2.y + xv.z * w2.z + xv.w * w2.w;
            acc[rr][3] += xv.x * w3.x + xv.y * w3.y + xv.z * w3.z + xv.w * w3.w;
        }
    }
    // ---- phase 3: |x|^2 quarter partials (batched, no shuffles) ----
    const int r = tid >> 2, q = tid & 3;
    {
        const float4* row4 = reinterpret_cast<const float4*>(xs + r * DD + q * 32);
        float s = 0.f;
#pragma unroll
        for (int i = 0; i < 8; ++i) {
            float4 v = row4[i];
            s += v.x * v.x + v.y * v.y + v.z * v.z + v.w * v.w;
        }
        sxq[tid] = s;
    }
    __syncthreads();
    // ---- overwrite tile with mx ----
#pragma unroll
    for (int rr = 0; rr < 8; ++rr)
#pragma unroll
        for (int cc = 0; cc < 4; ++cc)
            xs[(rg * 8 + rr) * DD + cc * 32 + c4] = acc[rr][cc];
    __syncthreads();
    // ---- phase 5: batched quarter-row dot products over mx ----
    {
        const float4* m4 = reinterpret_cast<const float4*>(xs + r * DD + q * 32);
        const float4* a4 = reinterpret_cast<const float4*>(atti + q * 32);
        const float4* b4 = reinterpret_cast<const float4*>(attj + q * 32);
        const float4* y4 = reinterpret_cast<const float4*>(hb + q * 32);
        float sm = 0.f, my = 0.f, di = 0.f, dj = 0.f;
#pragma unroll
        for (int i = 0; i < 8; ++i) {
            float4 m = m4[i], A = a4[i], B = b4[i], Y = y4[i];
            sm += m.x * m.x + m.y * m.y + m.z * m.z + m.w * m.w;
            my += m.x * Y.x + m.y * Y.y + m.z * Y.z + m.w * Y.w;
            di += m.x * A.x + m.y * A.y + m.z * A.z + m.w * A.w;
            dj += m.x * B.x + m.y * B.y + m.z * B.z + m.w * B.w;
        }
        float* o = sred + tid * 4;
        o[0] = sm; o[1] = my; o[2] = di; o[3] = dj;
    }
    __syncthreads();
    // ---- phase 6: per-row scalar chain (64 threads) ----
    if (tid < 64) {
        int grow = row0 + tid;
        float Sx = sxq[tid * 4] + sxq[tid * 4 + 1] + sxq[tid * 4 + 2] + sxq[tid * 4 + 3];
        const float* p0 = sred + tid * 16;
        float Sm  = p0[0] + p0[4] + p0[8] + p0[12];
        float My  = p0[1] + p0[5] + p0[9] + p0[13];
        float Di0 = p0[2] + p0[6];
        float Di1 = p0[10] + p0[14];
        float Dj0 = p0[3] + p0[7];
        float Dj1 = p0[11] + p0[15];
        float y2 = cst[0];
        // mobius_matvec: p = rho * mx
        float xn = fmaxf(sqrtf(Sx), 1e-15f);
        float mxn = fmaxf(sqrtf(Sm), 1e-15f);
        float art = atanhf(fminf(xn, 1.f - 1e-7f));
        float tn = tanhf(mxn / xn * art);
        float rho = (Sm == 0.f) ? 0.f : tn / mxn;
        float pn = (Sm == 0.f) ? 0.f : tn;  // |p| before proj
        if (pn > MAXN_F) { rho *= MAXN_F / pn; pn = MAXN_F; }
        // mobius_add(p, hb): h = (ca*p + cb*y)/dn
        float X2 = pn * pn, XY = rho * My;
        float ca = 1.f + 2.f * XY + y2;
        float cb = 1.f - X2;
        float dn = fmaxf(1.f + 2.f * XY + X2 * y2, 1e-15f);
        float Sh = (ca * ca * X2 + 2.f * ca * cb * XY + cb * cb * y2) / (dn * dn);
        // proj + logmap0: t = g*scp*h = alpha*mx + beta*y
        float nraw = fmaxf(sqrtf(Sh), 1e-15f);
        float scp = 1.f, nh = nraw;
        if (nraw > MAXN_F) { scp = MAXN_F / nraw; nh = MAXN_F; }
        float g = atanhf(fminf(nh, 1.f - 1e-7f)) / nh;
        float gs = g * scp / dn;
        float al = gs * ca * rho;
        float be = gs * cb;
        sab[tid * 2] = al;
        sab[tid * 2 + 1] = be;
        if (grow < n) {
            reinterpret_cast<float2*>(ai)[grow] =
                make_float2(al * Di0 + be * cst[1], al * Di1 + be * cst[2]);
            reinterpret_cast<float2*>(aj)[grow] =
                make_float2(al * Dj0 + be * cst[3], al * Dj1 + be * cst[4]);
        }
    }
    __syncthreads();
    // ---- phase 7: xt = alpha*mx + beta*hb (coalesced quarter writes) ----
    {
        int grow = row0 + r;
        if (grow < n) {
            float al = sab[r * 2], be = sab[r * 2 + 1];
            const float4* m4 = reinterpret_cast<const float4*>(xs + r * DD + q * 32);
            const float4* y4 = reinterpret_cast<const float4*>(hb + q * 32);
            float4* o4 = reinterpret_cast<float4*>(xt + (size_t)grow * DD + q * 32);
#pragma unroll
            for (int i = 0; i < 8; ++i) {
                float4 m = m4[i], Y = y4[i];
                o4[i] = make_float4(al * m.x + be * Y.x, al * m.y + be * Y.y,
                                    al * m.z + be * Y.z, al * m.w + be * Y.w);
            }
        }
    }
}

// ---------------- CSR build: histogram ----------------
__global__ __launch_bounds__(256) void count_k(const int* __restrict__ eidx,
                                               int* __restrict__ deg, int E) {
    int e = blockIdx.x * 256 + threadIdx.x;
    if (e >= E) return;
    atomicAdd(&deg[eidx[e]], 1);
}

// ---------------- scan: 3-level exclusive prefix sum ----------------
__global__ __launch_bounds__(256) void scan1_k(const int* __restrict__ deg,
                                               int* __restrict__ bsum, int n) {
    int b = blockIdx.x, tid = threadIdx.x;
    int i0 = b * 1024 + tid * 4;
    int s = 0;
#pragma unroll
    for (int k = 0; k < 4; ++k)
        if (i0 + k < n) s += deg[i0 + k];
    s = wsumi(s);
    __shared__ int sm[4];
    if ((tid & 63) == 0) sm[tid >> 6] = s;
    __syncthreads();
    if (tid == 0) bsum[b] = sm[0] + sm[1] + sm[2] + sm[3];
}

__global__ __launch_bounds__(256) void scan2_k(const int* __restrict__ bsum,
                                               int* __restrict__ bsoff, int nb) {
    int tid = threadIdx.x;
    __shared__ int sm[256];
    int v = (tid < nb) ? bsum[tid] : 0;
    sm[tid] = v;
    __syncthreads();
    for (int off = 1; off < 256; off <<= 1) {
        int u = (tid >= off) ? sm[tid - off] : 0;
        __syncthreads();
        sm[tid] += u;
        __syncthreads();
    }
    if (tid < nb) bsoff[tid] = sm[tid] - v;
}

__global__ __launch_bounds__(256) void scan3_k(const int* __restrict__ deg,
                                               const int* __restrict__ bsoff,
                                               int* __restrict__ rowptr,
                                               int* __restrict__ cursor, int n, int E) {
    int b = blockIdx.x, tid = threadIdx.x;
    int i0 = b * 1024 + tid * 4;
    int d[4];
#pragma unroll
    for (int k = 0; k < 4; ++k) d[k] = (i0 + k < n) ? deg[i0 + k] : 0;
    int ts = d[0] + d[1] + d[2] + d[3];
    __shared__ int sm[256];
    sm[tid] = ts;
    __syncthreads();
    for (int off = 1; off < 256; off <<= 1) {
        int u = (tid >= off) ? sm[tid - off] : 0;
        __syncthreads();
        sm[tid] += u;
        __syncthreads();
    }
    int base = bsoff[b] + sm[tid] - ts;
    int pre = 0;
#pragma unroll
    for (int k = 0; k < 4; ++k) {
        if (i0 + k < n) {
            rowptr[i0 + k] = base + pre;
            cursor[i0 + k] = base + pre;
        }
        pre += d[k];
    }
    if (b == 0 && tid == 0) rowptr[n] = E;
}

// ---------------- CSR build: scatter ----------------
__global__ __launch_bounds__(256) void scatter_k(const int* __restrict__ eidx,
                                                 int* __restrict__ cursor,
                                                 int* __restrict__ csrc, int E) {
    int e = blockIdx.x * 256 + threadIdx.x;
    if (e >= E) return;
    int t = eidx[e], s = eidx[E + e];
    int pos = atomicAdd(&cursor[t], 1);
    csrc[pos] = s;
}

// ---------------- fused softmax + aggregation + HypAct ----------------
// one wave per target node; CSR gather, no atomics.
__global__ __launch_bounds__(256) void agg_fused_k(
    const int* __restrict__ rowptr, const int* __restrict__ csrc,
    const float* __restrict__ ai, const float* __restrict__ aj,
    const float* __restrict__ xt, float* __restrict__ out, int n) {
    int t = (blockIdx.x * 256 + threadIdx.x) >> 6;
    int lane = threadIdx.x & 63;
    if (t >= n) return;
    const int beg = rowptr[t];
    const int deg = rowptr[t + 1] - beg;
    const int cnt = deg + 1;  // + self loop
    float2 ait = reinterpret_cast<const float2*>(ai)[t];
    const float2* aj2 = reinterpret_cast<const float2*>(aj);
    // pass 1: segment max
    float mx0 = -1e30f, mx1 = -1e30f;
    for (int bs = 0; bs < cnt; bs += 64) {
        int idx = bs + lane;
        float a0 = -1e30f, a1 = -1e30f;
        if (idx < cnt) {
            int s = (idx < deg) ? csrc[beg + idx] : t;
            float2 av = aj2[s];
            a0 = ait.x + av.x; a0 = a0 < 0.f ? 0.2f * a0 : a0;
            a1 = ait.y + av.y; a1 = a1 < 0.f ? 0.2f * a1 : a1;
        }
        mx0 = fmaxf(mx0, a0);
        mx1 = fmaxf(mx1, a1);
    }
    mx0 = wmax(mx0);
    mx1 = wmax(mx1);
    // pass 2: exp weights + denominator + weighted gather
    float acc0 = 0.f, acc1 = 0.f, den0 = 0.f, den1 = 0.f;
    for (int bs = 0; bs < cnt; bs += 64) {
        int idx = bs + lane;
        int s = t;
        float e0 = 0.f, e1 = 0.f;
        if (idx < cnt) {
            s = (idx < deg) ? csrc[beg + idx] : t;
            float2 av = aj2[s];
            float a0 = ait.x + av.x; a0 = a0 < 0.f ? 0.2f * a0 : a0;
            float a1 = ait.y + av.y; a1 = a1 < 0.f ? 0.2f * a1 : a1;
            e0 = expf(a0 - mx0);
            e1 = expf(a1 - mx1);
        }
        den0 += e0;
        den1 += e1;
        int m = min(64, cnt - bs);
        for (int j = 0; j < m; ++j) {
            int sj = __shfl(s, j, 64);
            float w0 = __shfl(e0, j, 64);
            float w1 = __shfl(e1, j, 64);
            size_t sb = (size_t)sj * DD;
            acc0 += w0 * xt[sb + lane];
            acc1 += w1 * xt[sb + 64 + lane];
        }
    }
    den0 = wsum(den0);
    den1 = wsum(den1);
    float u = 0.5f * (acc0 / (den0 + 1e-16f) + acc1 / (den1 + 1e-16f));
    // ---- HypAct: expmap0 -> proj -> logmap0 -> leaky -> expmap0 -> proj ----
    float Su = wsum(u * u);
    float nu = fmaxf(sqrtf(Su), 1e-15f);
    float e = tanhf(nu) * u / nu;
    float Se = wsum(e * e);
    float ne = fmaxf(sqrtf(Se), 1e-15f);
    if (ne > MAXN_F) e *= MAXN_F / ne;
    float Sh = wsum(e * e);
    float nh = fmaxf(sqrtf(Sh), 1e-15f);
    float g = atanhf(fminf(nh, 1.f - 1e-7f)) / nh;
    float ht = g * e;
    ht = ht < 0.f ? 0.01f * ht : ht;
    float St = wsum(ht * ht);
    float nt = fmaxf(sqrtf(St), 1e-15f);
    float o = tanhf(nt) * ht / nt;
    float So = wsum(o * o);
    float no = fmaxf(sqrtf(So), 1e-15f);
    if (no > MAXN_F) o *= MAXN_F / no;
    out[(size_t)t * DH + lane] = o;
}

extern "C" void kernel_launch(void* const* d_in, const int* in_sizes, int n_in,
                              void* d_out, int out_size, void* d_ws, size_t ws_size,
                              hipStream_t stream) {
    const float* x    = (const float*)d_in[0];
    const int*   eidx = (const int*)d_in[1];
    const float* W    = (const float*)d_in[2];
    const float* bias = (const float*)d_in[3];
    const float* atti = (const float*)d_in[4];
    const float* attj = (const float*)d_in[5];
    float* out = (float*)d_out;

    const int n = in_sizes[0] / DD;  // 100000
    const int E = in_sizes[1] / 2;   // 600000
    const size_t nf = (size_t)n;

    float* ws = (float*)d_ws;
    float* xt  = ws;                   // n*128
    float* ai  = xt + nf * DD;         // 2n
    float* aj  = ai + 2 * nf;          // 2n
    float* hb  = aj + 2 * nf;          // 128
    float* cst = hb + DD;              // 5 (+11 pad)
    int* deg    = (int*)(cst + 11);    // n (16B aligned)
    int* rowptr = deg + nf;            // n+1
    int* cursor = rowptr + nf + 1;     // n
    int* bsum   = cursor + nf;         // 256
    int* bsoff  = bsum + 256;          // 256
    int* csrc   = bsoff + 256;         // E

    const int nb = (n + 1023) / 1024;  // scan blocks (<=256)

    hipMemsetAsync(deg, 0, nf * sizeof(int), stream);
    bias_k<<<1, 128, 0, stream>>>(bias, atti, attj, hb, cst);
    gemm_node_k<<<(n + 63) / 64, 256, 0, stream>>>(x, W, hb, cst, atti, attj,
                                                   xt, ai, aj, n);
    count_k<<<(E + 255) / 256, 256, 0, stream>>>(eidx, deg, E);
    scan1_k<<<nb, 256, 0, stream>>>(deg, bsum, n);
    scan2_k<<<1, 256, 0, stream>>>(bsum, bsoff, nb);
    scan3_k<<<nb, 256, 0, stream>>>(deg, bsoff, rowptr, cursor, n, E);
    scatter_k<<<(E + 255) / 256, 256, 0, stream>>>(eidx, cursor, csrc, E);
    agg_fused_k<<<(n + 3) / 4, 256, 0, stream>>>(rowptr, csrc, ai, aj, xt, out, n);
}

// Round 11
// 301.711 us; speedup vs baseline: 1.7227x; 1.1206x over previous
//
#include <hip/hip_runtime.h>
#include <hip/hip_bf16.h>
#include <math.h>

#define DD 128
#define DH 64
#define MAXN_F (1.0f - 4e-3f)

__device__ inline float wsum(float v) {
#pragma unroll
    for (int off = 32; off > 0; off >>= 1) v += __shfl_xor(v, off, 64);
    return v;
}
__device__ inline float wmax(float v) {
#pragma unroll
    for (int off = 32; off > 0; off >>= 1) v = fmaxf(v, __shfl_xor(v, off, 64));
    return v;
}
__device__ inline int wsumi(int v) {
#pragma unroll
    for (int off = 32; off > 0; off >>= 1) v += __shfl_xor(v, off, 64);
    return v;
}

// ---------------- hyp bias: proj(expmap0(bias)) + constants ----------------
// cst = { y2=|hb|^2, Yi0, Yi1, Yj0, Yj1 }
__global__ void bias_k(const float* __restrict__ bias,
                       const float* __restrict__ atti, const float* __restrict__ attj,
                       float* __restrict__ hb, float* __restrict__ cst) {
    __shared__ float red[2];
    int tid = threadIdx.x;  // 0..127
    float b = bias[tid];
    float s = wsum(b * b);
    if ((tid & 63) == 0) red[tid >> 6] = s;
    __syncthreads();
    float S = red[0] + red[1];
    __syncthreads();
    float n = fmaxf(sqrtf(S), 1e-15f);
    float e = tanhf(n) * b / n;
    float s2 = wsum(e * e);
    if ((tid & 63) == 0) red[tid >> 6] = s2;
    __syncthreads();
    float ne = fmaxf(sqrtf(red[0] + red[1]), 1e-15f);
    __syncthreads();
    if (ne > MAXN_F) e *= MAXN_F / ne;
    hb[tid] = e;
    float s3 = wsum(e * e);
    if ((tid & 63) == 0) red[tid >> 6] = s3;
    __syncthreads();
    if (tid == 0) cst[0] = red[0] + red[1];
    float di = wsum(e * atti[tid]);
    float dj = wsum(e * attj[tid]);
    if ((tid & 63) == 0) {
        int h = tid >> 6;
        cst[1 + h] = di;
        cst[3 + h] = dj;
    }
}

// ---------------- fused GEMM (mx = x@W^T) + register-resident epilogue ------
// block 256 = 4 waves, 64 rows. acc[8][4] stays in registers; per-row scalars
// (Sm, My, Di/Dj per head) via 32-lane shfl_xor reductions (lanes sharing rg
// share rows). No mx LDS round-trip, no strided LDS reads, 3 barriers.
__global__ __launch_bounds__(256) void gemm_node_k(
    const float* __restrict__ x, const float* __restrict__ W,
    const float* __restrict__ hb, const float* __restrict__ cst,
    const float* __restrict__ atti, const float* __restrict__ attj,
    float* __restrict__ xt, float* __restrict__ ai, float* __restrict__ aj, int n) {
    __shared__ float xs[64 * DD];   // 32 KB x tile
    __shared__ float sred[6][64];   // {Sm,My,Di0,Di1,Dj0,Dj1} per row
    __shared__ float sxq[64];       // |x|^2 per row
    __shared__ float sab[64 * 2];   // alpha,beta per row
    const int row0 = blockIdx.x * 64;
    const int tid = threadIdx.x;
    const float4* x4 = reinterpret_cast<const float4*>(x);
    float4* xs4 = reinterpret_cast<float4*>(xs);
    // ---- stage x tile + fused |x|^2 partials ----
    float px[8];
#pragma unroll
    for (int j = 0; j < 8; ++j) {
        int idx = tid + j * 256;          // row = (tid>>5) + 8j, col4 = tid&31
        int r = idx >> 5;
        float4 v = make_float4(0.f, 0.f, 0.f, 0.f);
        if (row0 + r < n) v = x4[(size_t)(row0 + r) * 32 + (idx & 31)];
        xs4[idx] = v;
        px[j] = v.x * v.x + v.y * v.y + v.z * v.z + v.w * v.w;
    }
#pragma unroll
    for (int j = 0; j < 8; ++j) {
#pragma unroll
        for (int off = 16; off > 0; off >>= 1) px[j] += __shfl_xor(px[j], off, 32);
    }
    if ((tid & 31) == 0) {
        int g = tid >> 5;
#pragma unroll
        for (int j = 0; j < 8; ++j) sxq[g + j * 8] = px[j];
    }
    __syncthreads();
    // ---- GEMM ----
    const int c4 = tid & 31;   // column base
    const int rg = tid >> 5;   // row group 0..7 (2 per wave)
    float acc[8][4];
#pragma unroll
    for (int rr = 0; rr < 8; ++rr)
#pragma unroll
        for (int cc = 0; cc < 4; ++cc) acc[rr][cc] = 0.f;
    const float4* W4 = reinterpret_cast<const float4*>(W);
    for (int k4 = 0; k4 < 32; ++k4) {
        float4 w0 = W4[(c4 + 0) * 32 + k4];
        float4 w1 = W4[(c4 + 32) * 32 + k4];
        float4 w2 = W4[(c4 + 64) * 32 + k4];
        float4 w3 = W4[(c4 + 96) * 32 + k4];
#pragma unroll
        for (int rr = 0; rr < 8; ++rr) {
            float4 xv = xs4[(rg * 8 + rr) * 32 + k4];
            acc[rr][0] += xv.x * w0.x + xv.y * w0.y + xv.z * w0.z + xv.w * w0.w;
            acc[rr][1] += xv.x * w1.x + xv.y * w1.y + xv.z * w1.z + xv.w * w1.w;
            acc[rr][2] += xv.x * w2.x + xv.y * w2.y + xv.z * w2.z + xv.w * w2.w;
            acc[rr][3] += xv.x * w3.x + xv.y * w3.y + xv.z * w3.z + xv.w * w3.w;
        }
    }
    // ---- register reductions: 6 per-row scalars via 32-lane shfl ----
    float hbv[4], aiv[4], ajv[4];
#pragma unroll
    for (int cc = 0; cc < 4; ++cc) {
        int c = cc * 32 + c4;
        hbv[cc] = hb[c];
        aiv[cc] = atti[c];
        ajv[cc] = attj[c];
    }
#pragma unroll
    for (int rr = 0; rr < 8; ++rr) {
        float m0 = acc[rr][0], m1 = acc[rr][1], m2 = acc[rr][2], m3 = acc[rr][3];
        float sm = m0 * m0 + m1 * m1 + m2 * m2 + m3 * m3;
        float my = m0 * hbv[0] + m1 * hbv[1] + m2 * hbv[2] + m3 * hbv[3];
        float d0 = m0 * aiv[0] + m1 * aiv[1];   // head0 = cols 0..63
        float d1 = m2 * aiv[2] + m3 * aiv[3];   // head1 = cols 64..127
        float e0 = m0 * ajv[0] + m1 * ajv[1];
        float e1 = m2 * ajv[2] + m3 * ajv[3];
#pragma unroll
        for (int off = 16; off > 0; off >>= 1) {
            sm += __shfl_xor(sm, off, 32);
            my += __shfl_xor(my, off, 32);
            d0 += __shfl_xor(d0, off, 32);
            d1 += __shfl_xor(d1, off, 32);
            e0 += __shfl_xor(e0, off, 32);
            e1 += __shfl_xor(e1, off, 32);
        }
        if (c4 == 0) {
            int row = rg * 8 + rr;
            sred[0][row] = sm; sred[1][row] = my;
            sred[2][row] = d0; sred[3][row] = d1;
            sred[4][row] = e0; sred[5][row] = e1;
        }
    }
    __syncthreads();
    // ---- per-row scalar chain (64 threads) ----
    if (tid < 64) {
        int grow = row0 + tid;
        float Sx  = sxq[tid];
        float Sm  = sred[0][tid];
        float My  = sred[1][tid];
        float Di0 = sred[2][tid];
        float Di1 = sred[3][tid];
        float Dj0 = sred[4][tid];
        float Dj1 = sred[5][tid];
        float y2 = cst[0];
        // mobius_matvec: p = rho * mx
        float xn = fmaxf(sqrtf(Sx), 1e-15f);
        float mxn = fmaxf(sqrtf(Sm), 1e-15f);
        float art = atanhf(fminf(xn, 1.f - 1e-7f));
        float tn = tanhf(mxn / xn * art);
        float rho = (Sm == 0.f) ? 0.f : tn / mxn;
        float pn = (Sm == 0.f) ? 0.f : tn;
        if (pn > MAXN_F) { rho *= MAXN_F / pn; pn = MAXN_F; }
        // mobius_add(p, hb): h = (ca*p + cb*y)/dn
        float X2 = pn * pn, XY = rho * My;
        float ca = 1.f + 2.f * XY + y2;
        float cb = 1.f - X2;
        float dn = fmaxf(1.f + 2.f * XY + X2 * y2, 1e-15f);
        float Sh = (ca * ca * X2 + 2.f * ca * cb * XY + cb * cb * y2) / (dn * dn);
        // proj + logmap0: t = alpha*mx + beta*hb
        float nraw = fmaxf(sqrtf(Sh), 1e-15f);
        float scp = 1.f, nh = nraw;
        if (nraw > MAXN_F) { scp = MAXN_F / nraw; nh = MAXN_F; }
        float g = atanhf(fminf(nh, 1.f - 1e-7f)) / nh;
        float gs = g * scp / dn;
        float al = gs * ca * rho;
        float be = gs * cb;
        sab[tid * 2] = al;
        sab[tid * 2 + 1] = be;
        if (grow < n) {
            reinterpret_cast<float2*>(ai)[grow] =
                make_float2(al * Di0 + be * cst[1], al * Di1 + be * cst[2]);
            reinterpret_cast<float2*>(aj)[grow] =
                make_float2(al * Dj0 + be * cst[3], al * Dj1 + be * cst[4]);
        }
    }
    __syncthreads();
    // ---- xt = alpha*acc + beta*hb straight from registers ----
#pragma unroll
    for (int rr = 0; rr < 8; ++rr) {
        int row = rg * 8 + rr;
        int grow = row0 + row;
        if (grow < n) {
            float al = sab[row * 2], be = sab[row * 2 + 1];
#pragma unroll
            for (int cc = 0; cc < 4; ++cc)
                xt[(size_t)grow * DD + cc * 32 + c4] = al * acc[rr][cc] + be * hbv[cc];
        }
    }
}

// ---------------- CSR build: histogram ----------------
__global__ __launch_bounds__(256) void count_k(const int* __restrict__ eidx,
                                               int* __restrict__ deg, int E) {
    int e = blockIdx.x * 256 + threadIdx.x;
    if (e >= E) return;
    atomicAdd(&deg[eidx[e]], 1);
}

// ---------------- scan: 3-level exclusive prefix sum ----------------
__global__ __launch_bounds__(256) void scan1_k(const int* __restrict__ deg,
                                               int* __restrict__ bsum, int n) {
    int b = blockIdx.x, tid = threadIdx.x;
    int i0 = b * 1024 + tid * 4;
    int s = 0;
#pragma unroll
    for (int k = 0; k < 4; ++k)
        if (i0 + k < n) s += deg[i0 + k];
    s = wsumi(s);
    __shared__ int sm[4];
    if ((tid & 63) == 0) sm[tid >> 6] = s;
    __syncthreads();
    if (tid == 0) bsum[b] = sm[0] + sm[1] + sm[2] + sm[3];
}

__global__ __launch_bounds__(256) void scan2_k(const int* __restrict__ bsum,
                                               int* __restrict__ bsoff, int nb) {
    int tid = threadIdx.x;
    __shared__ int sm[256];
    int v = (tid < nb) ? bsum[tid] : 0;
    sm[tid] = v;
    __syncthreads();
    for (int off = 1; off < 256; off <<= 1) {
        int u = (tid >= off) ? sm[tid - off] : 0;
        __syncthreads();
        sm[tid] += u;
        __syncthreads();
    }
    if (tid < nb) bsoff[tid] = sm[tid] - v;
}

__global__ __launch_bounds__(256) void scan3_k(const int* __restrict__ deg,
                                               const int* __restrict__ bsoff,
                                               int* __restrict__ rowptr,
                                               int* __restrict__ cursor, int n, int E) {
    int b = blockIdx.x, tid = threadIdx.x;
    int i0 = b * 1024 + tid * 4;
    int d[4];
#pragma unroll
    for (int k = 0; k < 4; ++k) d[k] = (i0 + k < n) ? deg[i0 + k] : 0;
    int ts = d[0] + d[1] + d[2] + d[3];
    __shared__ int sm[256];
    sm[tid] = ts;
    __syncthreads();
    for (int off = 1; off < 256; off <<= 1) {
        int u = (tid >= off) ? sm[tid - off] : 0;
        __syncthreads();
        sm[tid] += u;
        __syncthreads();
    }
    int base = bsoff[b] + sm[tid] - ts;
    int pre = 0;
#pragma unroll
    for (int k = 0; k < 4; ++k) {
        if (i0 + k < n) {
            rowptr[i0 + k] = base + pre;
            cursor[i0 + k] = base + pre;
        }
        pre += d[k];
    }
    if (b == 0 && tid == 0) rowptr[n] = E;
}

// ---------------- CSR build: scatter ----------------
__global__ __launch_bounds__(256) void scatter_k(const int* __restrict__ eidx,
                                                 int* __restrict__ cursor,
                                                 int* __restrict__ csrc, int E) {
    int e = blockIdx.x * 256 + threadIdx.x;
    if (e >= E) return;
    int t = eidx[e], s = eidx[E + e];
    int pos = atomicAdd(&cursor[t], 1);
    csrc[pos] = s;
}

// ---------------- fused softmax + aggregation + HypAct ----------------
// one wave per target node; CSR gather, no atomics. Fast path deg<=63:
// logits/exp computed once in registers, 0.5/den folded into per-lane weight.
__global__ __launch_bounds__(256) void agg_fused_k(
    const int* __restrict__ rowptr, const int* __restrict__ csrc,
    const float* __restrict__ ai, const float* __restrict__ aj,
    const float* __restrict__ xt, float* __restrict__ out, int n) {
    int t = (blockIdx.x * 256 + threadIdx.x) >> 6;
    int lane = threadIdx.x & 63;
    if (t >= n) return;
    const int beg = rowptr[t];
    const int deg = rowptr[t + 1] - beg;
    const int cnt = deg + 1;  // + self loop
    float2 ait = reinterpret_cast<const float2*>(ai)[t];
    const float2* aj2 = reinterpret_cast<const float2*>(aj);
    float u;
    if (cnt <= 64) {
        // ---- single-pass fast path ----
        int s_ = t;
        if (lane < deg) s_ = csrc[beg + lane];
        float a0 = -1e30f, a1 = -1e30f;
        if (lane < cnt) {
            float2 av = aj2[s_];
            a0 = ait.x + av.x; a0 = a0 < 0.f ? 0.2f * a0 : a0;
            a1 = ait.y + av.y; a1 = a1 < 0.f ? 0.2f * a1 : a1;
        }
        float mx0 = wmax(a0), mx1 = wmax(a1);
        float e0 = (lane < cnt) ? expf(a0 - mx0) : 0.f;
        float e1 = (lane < cnt) ? expf(a1 - mx1) : 0.f;
        float den0 = wsum(e0), den1 = wsum(e1);
        float w0s = 0.5f * e0 / (den0 + 1e-16f);
        float w1s = 0.5f * e1 / (den1 + 1e-16f);
        float acc = 0.f;
        for (int j = 0; j < cnt; ++j) {
            int sj = __shfl(s_, j, 64);
            float w0 = __shfl(w0s, j, 64);
            float w1 = __shfl(w1s, j, 64);
            size_t sb = (size_t)sj * DD;
            acc += w0 * xt[sb + lane] + w1 * xt[sb + 64 + lane];
        }
        u = acc;
    } else {
        // ---- general two-pass path ----
        float mx0 = -1e30f, mx1 = -1e30f;
        for (int bs = 0; bs < cnt; bs += 64) {
            int idx = bs + lane;
            float a0 = -1e30f, a1 = -1e30f;
            if (idx < cnt) {
                int s = (idx < deg) ? csrc[beg + idx] : t;
                float2 av = aj2[s];
                a0 = ait.x + av.x; a0 = a0 < 0.f ? 0.2f * a0 : a0;
                a1 = ait.y + av.y; a1 = a1 < 0.f ? 0.2f * a1 : a1;
            }
            mx0 = fmaxf(mx0, a0);
            mx1 = fmaxf(mx1, a1);
        }
        mx0 = wmax(mx0);
        mx1 = wmax(mx1);
        float acc0 = 0.f, acc1 = 0.f, den0 = 0.f, den1 = 0.f;
        for (int bs = 0; bs < cnt; bs += 64) {
            int idx = bs + lane;
            int s = t;
            float e0 = 0.f, e1 = 0.f;
            if (idx < cnt) {
                s = (idx < deg) ? csrc[beg + idx] : t;
                float2 av = aj2[s];
                float a0 = ait.x + av.x; a0 = a0 < 0.f ? 0.2f * a0 : a0;
                float a1 = ait.y + av.y; a1 = a1 < 0.f ? 0.2f * a1 : a1;
                e0 = expf(a0 - mx0);
                e1 = expf(a1 - mx1);
            }
            den0 += e0;
            den1 += e1;
            int m = min(64, cnt - bs);
            for (int j = 0; j < m; ++j) {
                int sj = __shfl(s, j, 64);
                float w0 = __shfl(e0, j, 64);
                float w1 = __shfl(e1, j, 64);
                size_t sb = (size_t)sj * DD;
                acc0 += w0 * xt[sb + lane];
                acc1 += w1 * xt[sb + 64 + lane];
            }
        }
        den0 = wsum(den0);
        den1 = wsum(den1);
        u = 0.5f * (acc0 / (den0 + 1e-16f) + acc1 / (den1 + 1e-16f));
    }
    // ---- HypAct: expmap0 -> proj -> logmap0 -> leaky -> expmap0 -> proj ----
    float Su = wsum(u * u);
    float nu = fmaxf(sqrtf(Su), 1e-15f);
    float e = tanhf(nu) * u / nu;
    float Se = wsum(e * e);
    float ne = fmaxf(sqrtf(Se), 1e-15f);
    if (ne > MAXN_F) e *= MAXN_F / ne;
    float Sh = wsum(e * e);
    float nh = fmaxf(sqrtf(Sh), 1e-15f);
    float g = atanhf(fminf(nh, 1.f - 1e-7f)) / nh;
    float ht = g * e;
    ht = ht < 0.f ? 0.01f * ht : ht;
    float St = wsum(ht * ht);
    float nt = fmaxf(sqrtf(St), 1e-15f);
    float o = tanhf(nt) * ht / nt;
    float So = wsum(o * o);
    float no = fmaxf(sqrtf(So), 1e-15f);
    if (no > MAXN_F) o *= MAXN_F / no;
    out[(size_t)t * DH + lane] = o;
}

extern "C" void kernel_launch(void* const* d_in, const int* in_sizes, int n_in,
                              void* d_out, int out_size, void* d_ws, size_t ws_size,
                              hipStream_t stream) {
    const float* x    = (const float*)d_in[0];
    const int*   eidx = (const int*)d_in[1];
    const float* W    = (const float*)d_in[2];
    const float* bias = (const float*)d_in[3];
    const float* atti = (const float*)d_in[4];
    const float* attj = (const float*)d_in[5];
    float* out = (float*)d_out;

    const int n = in_sizes[0] / DD;  // 100000
    const int E = in_sizes[1] / 2;   // 600000
    const size_t nf = (size_t)n;

    float* ws = (float*)d_ws;
    float* xt  = ws;                   // n*128
    float* ai  = xt + nf * DD;         // 2n
    float* aj  = ai + 2 * nf;          // 2n
    float* hb  = aj + 2 * nf;          // 128
    float* cst = hb + DD;              // 5 (+11 pad)
    int* deg    = (int*)(cst + 11);    // n (16B aligned)
    int* rowptr = deg + nf;            // n+1
    int* cursor = rowptr + nf + 1;     // n
    int* bsum   = cursor + nf;         // 256
    int* bsoff  = bsum + 256;          // 256
    int* csrc   = bsoff + 256;         // E

    const int nb = (n + 1023) / 1024;  // scan blocks (<=256)

    hipMemsetAsync(deg, 0, nf * sizeof(int), stream);
    bias_k<<<1, 128, 0, stream>>>(bias, atti, attj, hb, cst);
    gemm_node_k<<<(n + 63) / 64, 256, 0, stream>>>(x, W, hb, cst, atti, attj,
                                                   xt, ai, aj, n);
    count_k<<<(E + 255) / 256, 256, 0, stream>>>(eidx, deg, E);
    scan1_k<<<nb, 256, 0, stream>>>(deg, bsum, n);
    scan2_k<<<1, 256, 0, stream>>>(bsum, bsoff, nb);
    scan3_k<<<nb, 256, 0, stream>>>(deg, bsoff, rowptr, cursor, n, E);
    scatter_k<<<(E + 255) / 256, 256, 0, stream>>>(eidx, cursor, csrc, E);
    agg_fused_k<<<(n + 3) / 4, 256, 0, stream>>>(rowptr, csrc, ai, aj, xt, out, n);
}